// Round 1
// baseline (265.104 us; speedup 1.0000x reference)
//
#include <hip/hip_runtime.h>
#include <hip/hip_bf16.h>
#include <math.h>

#define NH 16
#define HS 64
#define DE 1024
#define TT 1024
#define BBATCH 4
#define MTOK 4096   // B*T

typedef __bf16 v8bf __attribute__((ext_vector_type(8)));
typedef __bf16 v4bf __attribute__((ext_vector_type(4)));
typedef float  v4f  __attribute__((ext_vector_type(4)));

__device__ __forceinline__ void gl_lds16(const __bf16* g, __bf16* l) {
    __builtin_amdgcn_global_load_lds(
        (const __attribute__((address_space(1))) unsigned int*)g,
        (__attribute__((address_space(3))) unsigned int*)l, 16, 0, 0);
}

// ---------------- cast fp32 -> bf16, 4 elements/thread ----------------
__global__ __launch_bounds__(256) void cast_bf16_kernel(
    const float* __restrict__ in, __bf16* __restrict__ out, int n4)
{
    int i = blockIdx.x * 256 + threadIdx.x;
    if (i >= n4) return;
    float4 v = ((const float4*)in)[i];
    v4bf o;
    o[0] = (__bf16)v.x; o[1] = (__bf16)v.y; o[2] = (__bf16)v.z; o[3] = (__bf16)v.w;
    *(v4bf*)&out[(size_t)i * 4] = o;
}

// --------- transpose+cast Wq/Wk/Wv [H][C][S] -> Wt[(m*1024+h*64+s)][c] ---------
__global__ __launch_bounds__(256) void prep_w_kernel(
    const float* __restrict__ Wq, const float* __restrict__ Wk,
    const float* __restrict__ Wv, __bf16* __restrict__ Wt)
{
    int m = blockIdx.z, h = blockIdx.y, c0 = blockIdx.x * 64;
    const float* W = (m == 0) ? Wq : (m == 1) ? Wk : Wv;
    __shared__ float tile[64][65];
    int t = threadIdx.x;
    #pragma unroll
    for (int pp = 0; pp < 16; ++pp) {
        int cl = pp * 4 + (t >> 6);
        int s  = t & 63;
        tile[cl][s] = W[((size_t)h * DE + c0 + cl) * HS + s];
    }
    __syncthreads();
    #pragma unroll
    for (int pp = 0; pp < 16; ++pp) {
        int s  = pp * 4 + (t >> 6);
        int cl = t & 63;
        Wt[((size_t)(m * DE + h * HS + s)) * DE + c0 + cl] = (__bf16)tile[cl][s];
    }
}

// ---------------- 128x128 MFMA GEMM, A[M][K] x Bt[N][K]^T ----------------
// mode 0: QKV. cols 0..2047 -> qk_out[token][2048] bf16; cols 2048.. -> vt[bh][s][t]
// mode 1: out proj. f_out[token][1024] fp32 + bias
__global__ __launch_bounds__(256) void gemm_bt_kernel(
    const __bf16* __restrict__ A, const __bf16* __restrict__ Bt,
    int K, int mode,
    __bf16* __restrict__ qk_out, __bf16* __restrict__ vt_out,
    float* __restrict__ f_out, const float* __restrict__ bias)
{
    __shared__ __align__(16) __bf16 As[128 * 64];
    __shared__ __align__(16) __bf16 Bs[128 * 64];
    const int tid = threadIdx.x;
    const int w = tid >> 6, l = tid & 63;
    const int wm = w >> 1, wn = w & 1;
    const int lhi = l >> 4, llo = l & 15;
    const int bm = blockIdx.y, bn = blockIdx.x;

    v4f acc[4][4];
    #pragma unroll
    for (int i = 0; i < 4; ++i)
        #pragma unroll
        for (int j = 0; j < 4; ++j)
            #pragma unroll
            for (int r = 0; r < 4; ++r) acc[i][j][r] = 0.f;

    const __bf16* Ab = A  + (size_t)bm * 128 * K;
    const __bf16* Bb = Bt + (size_t)bn * 128 * K;

    for (int k0 = 0; k0 < K; k0 += 64) {
        __syncthreads();
        #pragma unroll
        for (int i = 0; i < 4; ++i) {
            int chunk = i * 256 + w * 64 + l;
            gl_lds16(Ab + (size_t)(chunk >> 3) * K + k0 + (chunk & 7) * 8,
                     &As[(i * 256 + w * 64) * 8]);
            gl_lds16(Bb + (size_t)(chunk >> 3) * K + k0 + (chunk & 7) * 8,
                     &Bs[(i * 256 + w * 64) * 8]);
        }
        __syncthreads();
        #pragma unroll
        for (int kk = 0; kk < 64; kk += 32) {
            v8bf a[4], b[4];
            #pragma unroll
            for (int i = 0; i < 4; ++i)
                a[i] = *(const v8bf*)&As[(wm * 64 + i * 16 + llo) * 64 + kk + lhi * 8];
            #pragma unroll
            for (int j = 0; j < 4; ++j)
                b[j] = *(const v8bf*)&Bs[(wn * 64 + j * 16 + llo) * 64 + kk + lhi * 8];
            #pragma unroll
            for (int i = 0; i < 4; ++i)
                #pragma unroll
                for (int j = 0; j < 4; ++j)
                    acc[i][j] = __builtin_amdgcn_mfma_f32_16x16x32_bf16(a[i], b[j], acc[i][j], 0, 0, 0);
        }
    }

    const int row0 = bm * 128 + wm * 64;
    const int col0 = bn * 128 + wn * 64;

    if (mode == 0) {
        if (col0 < 2048) {   // Q / K region
            #pragma unroll
            for (int i = 0; i < 4; ++i) {
                int rbase = row0 + i * 16 + lhi * 4;
                #pragma unroll
                for (int j = 0; j < 4; ++j) {
                    int c = col0 + j * 16 + llo;
                    #pragma unroll
                    for (int r = 0; r < 4; ++r)
                        qk_out[(size_t)(rbase + r) * 2048 + c] = (__bf16)acc[i][j][r];
                }
            }
        } else {             // V region -> vt[(b*16+h)*64+s][t], packed 4 t's
            #pragma unroll
            for (int i = 0; i < 4; ++i) {
                int rbase = row0 + i * 16 + lhi * 4;
                int bidx = rbase >> 10, t0 = rbase & 1023;
                #pragma unroll
                for (int j = 0; j < 4; ++j) {
                    int c = col0 + j * 16 + llo - 2048;   // h*64+s
                    v4bf pk;
                    #pragma unroll
                    for (int r = 0; r < 4; ++r) pk[r] = (__bf16)acc[i][j][r];
                    *(v4bf*)&vt_out[((size_t)(bidx * NH + (c >> 6)) * HS + (c & 63)) * TT + t0] = pk;
                }
            }
        }
    } else {
        #pragma unroll
        for (int j = 0; j < 4; ++j) {
            int c = col0 + j * 16 + llo;
            float bv = bias[c];
            #pragma unroll
            for (int i = 0; i < 4; ++i) {
                int rbase = row0 + i * 16 + lhi * 4;
                #pragma unroll
                for (int r = 0; r < 4; ++r)
                    f_out[(size_t)(rbase + r) * DE + c] = acc[i][j][r] + bv;
            }
        }
    }
}

// ---------------- flash attention: block = 64 q rows x one (b,h) ----------------
__global__ __launch_bounds__(256) void attn_kernel(
    const __bf16* __restrict__ qk, const __bf16* __restrict__ vt,
    __bf16* __restrict__ att)
{
    __shared__ __align__(16) __bf16 Qs[64][64];
    __shared__ __align__(16) __bf16 Ks[64][64];
    __shared__ __align__(16) __bf16 Vst[64][64];   // [s][kv]
    __shared__ __align__(16) __bf16 Ps[4][16][64]; // per-wave P

    const int tid = threadIdx.x;
    const int w = tid >> 6, l = tid & 63;
    const int lhi = l >> 4, llo = l & 15;
    const int qt = blockIdx.x, bh = blockIdx.y;
    const int b = bh >> 4, h = bh & 15;
    const int q0 = qt * 64;

    #pragma unroll
    for (int pp = 0; pp < 2; ++pp) {
        int c = pp * 256 + tid;
        int r = c >> 3, cc = (c & 7) * 8;
        *(int4*)&Qs[r][cc] = *(const int4*)&qk[((size_t)(b * TT + q0 + r)) * 2048 + h * HS + cc];
    }

    float m_i[4], l_i[4];
    v4f o[4];
    #pragma unroll
    for (int r = 0; r < 4; ++r) { m_i[r] = -1e30f; l_i[r] = 0.f; }
    #pragma unroll
    for (int n = 0; n < 4; ++n)
        #pragma unroll
        for (int r = 0; r < 4; ++r) o[n][r] = 0.f;

    for (int kt = 0; kt <= qt; ++kt) {
        int k0 = kt * 64;
        __syncthreads();
        #pragma unroll
        for (int pp = 0; pp < 2; ++pp) {
            int c = pp * 256 + tid;
            int r = c >> 3, cc = (c & 7) * 8;
            *(int4*)&Ks[r][cc]  = *(const int4*)&qk[((size_t)(b * TT + k0 + r)) * 2048 + 1024 + h * HS + cc];
            *(int4*)&Vst[r][cc] = *(const int4*)&vt[((size_t)(bh * HS + r)) * TT + k0 + cc];
        }
        __syncthreads();

        // S = Q K^T  (per wave: 16 q rows x 64 keys)
        v4f sacc[4];
        #pragma unroll
        for (int n = 0; n < 4; ++n)
            #pragma unroll
            for (int r = 0; r < 4; ++r) sacc[n][r] = 0.f;
        #pragma unroll
        for (int kk = 0; kk < 64; kk += 32) {
            v8bf aq = *(const v8bf*)&Qs[w * 16 + llo][kk + lhi * 8];
            #pragma unroll
            for (int n = 0; n < 4; ++n) {
                v8bf bk = *(const v8bf*)&Ks[n * 16 + llo][kk + lhi * 8];
                sacc[n] = __builtin_amdgcn_mfma_f32_16x16x32_bf16(aq, bk, sacc[n], 0, 0, 0);
            }
        }

        // online softmax (rows = lhi*4 + r, cols = n*16 + llo)
        const bool diag = (kt == qt);
        float prob[4][4];
        #pragma unroll
        for (int r = 0; r < 4; ++r) {
            int rowg = q0 + w * 16 + lhi * 4 + r;
            float sv[4];
            float mx = -1e30f;
            #pragma unroll
            for (int n = 0; n < 4; ++n) {
                float v = sacc[n][r] * 0.125f;
                if (diag) { int colg = k0 + n * 16 + llo; if (colg > rowg) v = -1e30f; }
                sv[n] = v;
                mx = fmaxf(mx, v);
            }
            #pragma unroll
            for (int msk = 1; msk < 16; msk <<= 1) mx = fmaxf(mx, __shfl_xor(mx, msk, 64));
            float mnew = fmaxf(m_i[r], mx);
            float alpha = __expf(m_i[r] - mnew);
            m_i[r] = mnew;
            float rs = 0.f;
            #pragma unroll
            for (int n = 0; n < 4; ++n) { float pv = __expf(sv[n] - mnew); prob[n][r] = pv; rs += pv; }
            #pragma unroll
            for (int msk = 1; msk < 16; msk <<= 1) rs += __shfl_xor(rs, msk, 64);
            l_i[r] = l_i[r] * alpha + rs;
            #pragma unroll
            for (int n = 0; n < 4; ++n) o[n][r] *= alpha;
        }

        // P: C-layout -> LDS -> A-layout (per-wave region; DS ops in-order within wave)
        #pragma unroll
        for (int r = 0; r < 4; ++r)
            #pragma unroll
            for (int n = 0; n < 4; ++n)
                Ps[w][lhi * 4 + r][n * 16 + llo] = (__bf16)prob[n][r];

        // O += P V
        #pragma unroll
        for (int kk = 0; kk < 64; kk += 32) {
            v8bf ap = *(const v8bf*)&Ps[w][llo][kk + lhi * 8];
            #pragma unroll
            for (int n = 0; n < 4; ++n) {
                v8bf bv = *(const v8bf*)&Vst[n * 16 + llo][kk + lhi * 8];
                o[n] = __builtin_amdgcn_mfma_f32_16x16x32_bf16(ap, bv, o[n], 0, 0, 0);
            }
        }
    }

    #pragma unroll
    for (int r = 0; r < 4; ++r) {
        int rowg = b * TT + q0 + w * 16 + lhi * 4 + r;
        float inv = 1.f / l_i[r];
        #pragma unroll
        for (int n = 0; n < 4; ++n)
            att[(size_t)rowg * DE + h * HS + n * 16 + llo] = (__bf16)(o[n][r] * inv);
    }
}

extern "C" void kernel_launch(void* const* d_in, const int* in_sizes, int n_in,
                              void* d_out, int out_size, void* d_ws, size_t ws_size,
                              hipStream_t stream)
{
    const float* x  = (const float*)d_in[0];
    const float* Wq = (const float*)d_in[1];
    const float* Wk = (const float*)d_in[2];
    const float* Wv = (const float*)d_in[3];
    const float* Wo = (const float*)d_in[4];
    const float* bo = (const float*)d_in[5];
    float* out = (float*)d_out;

    char* ws = (char*)d_ws;
    __bf16* xb  = (__bf16*)(ws);                 // 8 MB   [4096][1024]
    __bf16* Wt  = (__bf16*)(ws + 8388608);       // 6 MB   [3072][1024]
    __bf16* Wob = (__bf16*)(ws + 14680064);      // 2 MB   [1024][1024]
    __bf16* qk  = (__bf16*)(ws + 16777216);      // 16 MB  [4096][2048]
    __bf16* vt  = (__bf16*)(ws + 33554432);      // 8 MB   [64][64][1024]
    __bf16* att = (__bf16*)(ws + 41943040);      // 8 MB   [4096][1024]

    cast_bf16_kernel<<<4096, 256, 0, stream>>>(x, xb, 1048576);
    prep_w_kernel<<<dim3(16, 16, 3), 256, 0, stream>>>(Wq, Wk, Wv, Wt);
    cast_bf16_kernel<<<1024, 256, 0, stream>>>(Wo, Wob, 262144);
    // QKV: M=4096, N=3072, K=1024
    gemm_bt_kernel<<<dim3(24, 32), 256, 0, stream>>>(xb, Wt, 1024, 0, qk, vt, nullptr, nullptr);
    // attention: 16 q-tiles x 64 (b,h)
    attn_kernel<<<dim3(16, 64), 256, 0, stream>>>(qk, vt, att);
    // out proj: M=4096, N=1024, K=1024
    gemm_bt_kernel<<<dim3(8, 32), 256, 0, stream>>>(att, Wob, 1024, 1, nullptr, nullptr, out, bo);
}

// Round 2
// 233.019 us; speedup vs baseline: 1.1377x; 1.1377x over previous
//
#include <hip/hip_runtime.h>
#include <hip/hip_bf16.h>
#include <math.h>

#define NH 16
#define HS 64
#define DE 1024
#define TT 1024
#define BBATCH 4
#define MTOK 4096   // B*T

typedef __bf16 v8bf __attribute__((ext_vector_type(8)));
typedef __bf16 v4bf __attribute__((ext_vector_type(4)));
typedef float  v4f  __attribute__((ext_vector_type(4)));

__device__ __forceinline__ void gl_lds16(const __bf16* g, __bf16* l) {
    __builtin_amdgcn_global_load_lds(
        (const __attribute__((address_space(1))) unsigned int*)g,
        (__attribute__((address_space(3))) unsigned int*)l, 16, 0, 0);
}

// ---------------- cast fp32 -> bf16, 4 elements/thread ----------------
__global__ __launch_bounds__(256) void cast_bf16_kernel(
    const float* __restrict__ in, __bf16* __restrict__ out, int n4)
{
    int i = blockIdx.x * 256 + threadIdx.x;
    if (i >= n4) return;
    float4 v = ((const float4*)in)[i];
    v4bf o;
    o[0] = (__bf16)v.x; o[1] = (__bf16)v.y; o[2] = (__bf16)v.z; o[3] = (__bf16)v.w;
    *(v4bf*)&out[(size_t)i * 4] = o;
}

// --------- transpose+cast Wq/Wk/Wv [H][C][S] -> Wt[(m*1024+h*64+s)][c] ---------
__global__ __launch_bounds__(256) void prep_w_kernel(
    const float* __restrict__ Wq, const float* __restrict__ Wk,
    const float* __restrict__ Wv, __bf16* __restrict__ Wt)
{
    int m = blockIdx.z, h = blockIdx.y, c0 = blockIdx.x * 64;
    const float* W = (m == 0) ? Wq : (m == 1) ? Wk : Wv;
    __shared__ float tile[64][65];
    int t = threadIdx.x;
    #pragma unroll
    for (int pp = 0; pp < 16; ++pp) {
        int cl = pp * 4 + (t >> 6);
        int s  = t & 63;
        tile[cl][s] = W[((size_t)h * DE + c0 + cl) * HS + s];
    }
    __syncthreads();
    #pragma unroll
    for (int pp = 0; pp < 16; ++pp) {
        int s  = pp * 4 + (t >> 6);
        int cl = t & 63;
        Wt[((size_t)(m * DE + h * HS + s)) * DE + c0 + cl] = (__bf16)tile[cl][s];
    }
}

// ---------------- 128x128 MFMA GEMM, A[M][K] x Bt[N][K]^T ----------------
// mode 0: QKV. cols 0..2047 -> qk_out[token][2048] bf16; cols 2048.. -> vt[bh][s][t]
// mode 1: out proj. f_out[token][1024] fp32 + bias
__global__ __launch_bounds__(256) void gemm_bt_kernel(
    const __bf16* __restrict__ A, const __bf16* __restrict__ Bt,
    int K, int mode,
    __bf16* __restrict__ qk_out, __bf16* __restrict__ vt_out,
    float* __restrict__ f_out, const float* __restrict__ bias)
{
    __shared__ __align__(16) __bf16 As[128 * 64];
    __shared__ __align__(16) __bf16 Bs[128 * 64];
    const int tid = threadIdx.x;
    const int w = tid >> 6, l = tid & 63;
    const int wm = w >> 1, wn = w & 1;
    const int lhi = l >> 4, llo = l & 15;
    const int bm = blockIdx.y, bn = blockIdx.x;

    v4f acc[4][4];
    #pragma unroll
    for (int i = 0; i < 4; ++i)
        #pragma unroll
        for (int j = 0; j < 4; ++j)
            #pragma unroll
            for (int r = 0; r < 4; ++r) acc[i][j][r] = 0.f;

    const __bf16* Ab = A  + (size_t)bm * 128 * K;
    const __bf16* Bb = Bt + (size_t)bn * 128 * K;

    for (int k0 = 0; k0 < K; k0 += 64) {
        __syncthreads();
        #pragma unroll
        for (int i = 0; i < 4; ++i) {
            int chunk = i * 256 + w * 64 + l;
            gl_lds16(Ab + (size_t)(chunk >> 3) * K + k0 + (chunk & 7) * 8,
                     &As[(i * 256 + w * 64) * 8]);
            gl_lds16(Bb + (size_t)(chunk >> 3) * K + k0 + (chunk & 7) * 8,
                     &Bs[(i * 256 + w * 64) * 8]);
        }
        __syncthreads();
        #pragma unroll
        for (int kk = 0; kk < 64; kk += 32) {
            v8bf a[4], b[4];
            #pragma unroll
            for (int i = 0; i < 4; ++i)
                a[i] = *(const v8bf*)&As[(wm * 64 + i * 16 + llo) * 64 + kk + lhi * 8];
            #pragma unroll
            for (int j = 0; j < 4; ++j)
                b[j] = *(const v8bf*)&Bs[(wn * 64 + j * 16 + llo) * 64 + kk + lhi * 8];
            #pragma unroll
            for (int i = 0; i < 4; ++i)
                #pragma unroll
                for (int j = 0; j < 4; ++j)
                    acc[i][j] = __builtin_amdgcn_mfma_f32_16x16x32_bf16(a[i], b[j], acc[i][j], 0, 0, 0);
        }
    }

    const int row0 = bm * 128 + wm * 64;
    const int col0 = bn * 128 + wn * 64;

    if (mode == 0) {
        if (col0 < 2048) {   // Q / K region
            #pragma unroll
            for (int i = 0; i < 4; ++i) {
                int rbase = row0 + i * 16 + lhi * 4;
                #pragma unroll
                for (int j = 0; j < 4; ++j) {
                    int c = col0 + j * 16 + llo;
                    #pragma unroll
                    for (int r = 0; r < 4; ++r)
                        qk_out[(size_t)(rbase + r) * 2048 + c] = (__bf16)acc[i][j][r];
                }
            }
        } else {             // V region -> vt[(b*16+h)*64+s][t], packed 4 t's
            #pragma unroll
            for (int i = 0; i < 4; ++i) {
                int rbase = row0 + i * 16 + lhi * 4;
                int bidx = rbase >> 10, t0 = rbase & 1023;
                #pragma unroll
                for (int j = 0; j < 4; ++j) {
                    int c = col0 + j * 16 + llo - 2048;   // h*64+s
                    v4bf pk;
                    #pragma unroll
                    for (int r = 0; r < 4; ++r) pk[r] = (__bf16)acc[i][j][r];
                    *(v4bf*)&vt_out[((size_t)(bidx * NH + (c >> 6)) * HS + (c & 63)) * TT + t0] = pk;
                }
            }
        }
    } else {
        #pragma unroll
        for (int j = 0; j < 4; ++j) {
            int c = col0 + j * 16 + llo;
            float bv = bias[c];
            #pragma unroll
            for (int i = 0; i < 4; ++i) {
                int rbase = row0 + i * 16 + lhi * 4;
                #pragma unroll
                for (int r = 0; r < 4; ++r)
                    f_out[(size_t)(rbase + r) * DE + c] = acc[i][j][r] + bv;
            }
        }
    }
}

// ---------------- flash attention v2: barrier-free, wave-autonomous ----------------
// Block = 4 waves; wave owns 16 q rows. Q fragment in registers (loop-invariant).
// K/V fragments read directly from global (L2-resident; same-bh blocks share an XCD).
// Causal balance: block handles q-supertiles p and 15-p -> every wave does 17 kv-iters.
__global__ __launch_bounds__(256) void attn_kernel(
    const __bf16* __restrict__ qk, const __bf16* __restrict__ vt,
    __bf16* __restrict__ att)
{
    __shared__ __align__(16) __bf16 Ps[4][16][64]; // per-wave P scratch, no barriers

    const int tid = threadIdx.x;
    const int w = tid >> 6, l = tid & 63;
    const int lhi = l >> 4, llo = l & 15;
    const int bh = blockIdx.x & 63;          // same-bh blocks 64 apart -> same XCD
    const int p  = blockIdx.x >> 6;          // pair index 0..7
    const int b = bh >> 4, h = bh & 15;

    const __bf16* qbase = qk + (size_t)b * TT * 2048 + h * HS;          // Q rows
    const __bf16* kbase = qk + (size_t)b * TT * 2048 + 1024 + h * HS;   // K rows
    const __bf16* vbase = vt + (size_t)bh * HS * TT;                    // V^T rows

    #pragma unroll
    for (int half = 0; half < 2; ++half) {
        const int qt = half ? (15 - p) : p;
        const int r0 = qt * 64 + w * 16;     // first q row of this wave

        // Q fragment: A[m=llo][k=lhi*8+j], two K-halves
        v8bf aq0 = *(const v8bf*)&qbase[(size_t)(r0 + llo) * 2048 + lhi * 8];
        v8bf aq1 = *(const v8bf*)&qbase[(size_t)(r0 + llo) * 2048 + 32 + lhi * 8];

        float m_i[4], l_i[4];
        v4f o[4];
        #pragma unroll
        for (int r = 0; r < 4; ++r) { m_i[r] = -1e30f; l_i[r] = 0.f; }
        #pragma unroll
        for (int n = 0; n < 4; ++n)
            #pragma unroll
            for (int r = 0; r < 4; ++r) o[n][r] = 0.f;

        const int nkv = qt + 1;
        for (int kt = 0; kt < nkv; ++kt) {
            const int k0 = kt * 64;

            // S = Q K^T : B frags straight from global (L2)
            v4f sacc[4];
            #pragma unroll
            for (int n = 0; n < 4; ++n)
                #pragma unroll
                for (int r = 0; r < 4; ++r) sacc[n][r] = 0.f;
            #pragma unroll
            for (int n = 0; n < 4; ++n) {
                v8bf bk0 = *(const v8bf*)&kbase[(size_t)(k0 + n * 16 + llo) * 2048 + lhi * 8];
                v8bf bk1 = *(const v8bf*)&kbase[(size_t)(k0 + n * 16 + llo) * 2048 + 32 + lhi * 8];
                sacc[n] = __builtin_amdgcn_mfma_f32_16x16x32_bf16(aq0, bk0, sacc[n], 0, 0, 0);
                sacc[n] = __builtin_amdgcn_mfma_f32_16x16x32_bf16(aq1, bk1, sacc[n], 0, 0, 0);
            }

            // online softmax (rows = lhi*4 + r, cols = n*16 + llo)
            const bool diag = (kt == qt);
            float prob[4][4];
            #pragma unroll
            for (int r = 0; r < 4; ++r) {
                int rowg = r0 + lhi * 4 + r;
                float sv[4];
                float mx = -1e30f;
                #pragma unroll
                for (int n = 0; n < 4; ++n) {
                    float v = sacc[n][r] * 0.125f;
                    if (diag) { int colg = k0 + n * 16 + llo; if (colg > rowg) v = -1e30f; }
                    sv[n] = v;
                    mx = fmaxf(mx, v);
                }
                #pragma unroll
                for (int msk = 1; msk < 16; msk <<= 1) mx = fmaxf(mx, __shfl_xor(mx, msk, 64));
                float mnew = fmaxf(m_i[r], mx);
                float alpha = __expf(m_i[r] - mnew);
                m_i[r] = mnew;
                float rs = 0.f;
                #pragma unroll
                for (int n = 0; n < 4; ++n) { float pv = __expf(sv[n] - mnew); prob[n][r] = pv; rs += pv; }
                #pragma unroll
                for (int msk = 1; msk < 16; msk <<= 1) rs += __shfl_xor(rs, msk, 64);
                l_i[r] = l_i[r] * alpha + rs;
                #pragma unroll
                for (int n = 0; n < 4; ++n) o[n][r] *= alpha;
            }

            // P: C-layout -> LDS -> A-layout (per-wave region; same-wave DS ordering)
            #pragma unroll
            for (int r = 0; r < 4; ++r)
                #pragma unroll
                for (int n = 0; n < 4; ++n)
                    Ps[w][lhi * 4 + r][n * 16 + llo] = (__bf16)prob[n][r];

            // O += P V : V frags straight from global (L2)
            #pragma unroll
            for (int kk = 0; kk < 64; kk += 32) {
                v8bf ap = *(const v8bf*)&Ps[w][llo][kk + lhi * 8];
                #pragma unroll
                for (int n = 0; n < 4; ++n) {
                    v8bf bv = *(const v8bf*)&vbase[(size_t)(n * 16 + llo) * TT + k0 + kk + lhi * 8];
                    o[n] = __builtin_amdgcn_mfma_f32_16x16x32_bf16(ap, bv, o[n], 0, 0, 0);
                }
            }
        }

        #pragma unroll
        for (int r = 0; r < 4; ++r) {
            int rowg = b * TT + r0 + lhi * 4 + r;
            float inv = 1.f / l_i[r];
            #pragma unroll
            for (int n = 0; n < 4; ++n)
                att[(size_t)rowg * DE + h * HS + n * 16 + llo] = (__bf16)(o[n][r] * inv);
        }
    }
}

extern "C" void kernel_launch(void* const* d_in, const int* in_sizes, int n_in,
                              void* d_out, int out_size, void* d_ws, size_t ws_size,
                              hipStream_t stream)
{
    const float* x  = (const float*)d_in[0];
    const float* Wq = (const float*)d_in[1];
    const float* Wk = (const float*)d_in[2];
    const float* Wv = (const float*)d_in[3];
    const float* Wo = (const float*)d_in[4];
    const float* bo = (const float*)d_in[5];
    float* out = (float*)d_out;

    char* ws = (char*)d_ws;
    __bf16* xb  = (__bf16*)(ws);                 // 8 MB   [4096][1024]
    __bf16* Wt  = (__bf16*)(ws + 8388608);       // 6 MB   [3072][1024]
    __bf16* Wob = (__bf16*)(ws + 14680064);      // 2 MB   [1024][1024]
    __bf16* qk  = (__bf16*)(ws + 16777216);      // 16 MB  [4096][2048]
    __bf16* vt  = (__bf16*)(ws + 33554432);      // 8 MB   [64][64][1024]
    __bf16* att = (__bf16*)(ws + 41943040);      // 8 MB   [4096][1024]

    cast_bf16_kernel<<<4096, 256, 0, stream>>>(x, xb, 1048576);
    prep_w_kernel<<<dim3(16, 16, 3), 256, 0, stream>>>(Wq, Wk, Wv, Wt);
    cast_bf16_kernel<<<1024, 256, 0, stream>>>(Wo, Wob, 262144);
    // QKV: M=4096, N=3072, K=1024
    gemm_bt_kernel<<<dim3(24, 32), 256, 0, stream>>>(xb, Wt, 1024, 0, qk, vt, nullptr, nullptr);
    // attention: 512 blocks = 64 bh x 8 balanced q-supertile pairs
    attn_kernel<<<512, 256, 0, stream>>>(qk, vt, att);
    // out proj: M=4096, N=1024, K=1024
    gemm_bt_kernel<<<dim3(8, 32), 256, 0, stream>>>(att, Wob, 1024, 1, nullptr, nullptr, out, bo);
}